// Round 1
// baseline (191.264 us; speedup 1.0000x reference)
//
#include <hip/hip_runtime.h>
#include <math.h>

// ---------------- workspace layout (float offsets) ----------------
#define NHEAD     10004
#define OFF_HEAD  0        // 10004 head logits (rows 0..10003)
#define OFF_H0    10004    // 512  projected vec, cluster 0
#define OFF_H1    10516    // 256
#define OFF_H2    10772    // 128
#define OFF_H3    10900    // 64
#define OFF_C0    10964    // 10000 cluster-0 logits
#define OFF_C1    20964    // 20000
#define OFF_C2    40964    // 40000
#define OFF_C3    80964    // 20000
#define OFF_PH    100964   // 626  per-block partial sum(exp) for head
#define OFF_P0    101590   // 625
#define OFF_P1    102215   // 1250
#define OFF_P2    103465   // 2500
#define OFF_P3    105965   // 1250
// total 107215 floats = ~419 KB of d_ws

__device__ __forceinline__ float wave_sum(float v) {
  v += __shfl_xor(v, 32, 64);
  v += __shfl_xor(v, 16, 64);
  v += __shfl_xor(v, 8, 64);
  v += __shfl_xor(v, 4, 64);
  v += __shfl_xor(v, 2, 64);
  v += __shfl_xor(v, 1, 64);
  return v;
}

// Kernel 1: dot(row, feature) for 10004 head rows + 960 projection rows.
// Blocks 0..625: head (16 rows each, last partial). Blocks 626..685: proj rows.
// Wave-per-row, float4 loads, feature in LDS.
__global__ __launch_bounds__(256) void head_proj_kernel(
    const float* __restrict__ feat, const float* __restrict__ head_w,
    const float* __restrict__ p0, const float* __restrict__ p1,
    const float* __restrict__ p2, const float* __restrict__ p3,
    float* __restrict__ ws) {
  __shared__ __align__(16) float sf[1024];
  ((float4*)sf)[threadIdx.x] = ((const float4*)feat)[threadIdx.x];
  __syncthreads();
  const float4* sf4 = (const float4*)sf;
  const int wave = threadIdx.x >> 6, lane = threadIdx.x & 63;
  const int b = blockIdx.x;

  if (b < 626) {  // head rows, contribute to head sum(exp)
    float esum = 0.f;
#pragma unroll
    for (int k = 0; k < 4; ++k) {
      int row = b * 16 + wave * 4 + k;
      if (row < NHEAD) {
        const float4* src4 = (const float4*)head_w + (size_t)row * 256;
        float acc = 0.f;
#pragma unroll
        for (int j = 0; j < 4; ++j) {
          float4 a = src4[lane + j * 64];
          float4 c = sf4[lane + j * 64];
          acc += a.x * c.x + a.y * c.y + a.z * c.z + a.w * c.w;
        }
        acc = wave_sum(acc);
        if (lane == 0) { ws[OFF_HEAD + row] = acc; esum += expf(acc); }
      }
    }
    __shared__ float wred[4];
    if (lane == 0) wred[wave] = esum;
    __syncthreads();
    if (threadIdx.x == 0) ws[OFF_PH + b] = wred[0] + wred[1] + wred[2] + wred[3];
  } else {        // projection rows: output ws[row] directly (layout matches)
    const int pb = b - 626;
#pragma unroll
    for (int k = 0; k < 4; ++k) {
      int row = NHEAD + pb * 16 + wave * 4 + k;  // 10004..10963
      const float* src;
      if (row < 10516)      src = p0 + (size_t)(row - 10004) * 1024;
      else if (row < 10772) src = p1 + (size_t)(row - 10516) * 1024;
      else if (row < 10900) src = p2 + (size_t)(row - 10772) * 1024;
      else                  src = p3 + (size_t)(row - 10900) * 1024;
      const float4* src4 = (const float4*)src;
      float acc = 0.f;
#pragma unroll
      for (int j = 0; j < 4; ++j) {
        float4 a = src4[lane + j * 64];
        float4 c = sf4[lane + j * 64];
        acc += a.x * c.x + a.y * c.y + a.z * c.z + a.w * c.w;
      }
      acc = wave_sum(acc);
      if (lane == 0) ws[row] = acc;
    }
  }
}

// Kernel 2: cluster logits. Wave-per-row, 16 rows/block. Projected vector in LDS.
// Blocks: [0,625) c0(h=512)  [625,1875) c1(h=256)  [1875,4375) c2(h=128)  [4375,5625) c3(h=64)
__global__ __launch_bounds__(256) void tail_kernel(
    const float* __restrict__ w0, const float* __restrict__ w1,
    const float* __restrict__ w2, const float* __restrict__ w3,
    float* __restrict__ ws) {
  __shared__ __align__(16) float sh[512];
  const int b = blockIdx.x;
  const float* w; int h, hoff, coff, poff, lb;
  if (b < 625)       { w = w0; h = 512; hoff = OFF_H0; coff = OFF_C0; poff = OFF_P0; lb = b; }
  else if (b < 1875) { w = w1; h = 256; hoff = OFF_H1; coff = OFF_C1; poff = OFF_P1; lb = b - 625; }
  else if (b < 4375) { w = w2; h = 128; hoff = OFF_H2; coff = OFF_C2; poff = OFF_P2; lb = b - 1875; }
  else               { w = w3; h = 64;  hoff = OFF_H3; coff = OFF_C3; poff = OFF_P3; lb = b - 4375; }
  for (int t = threadIdx.x; t < h; t += 256) sh[t] = ws[hoff + t];
  __syncthreads();
  const int wave = threadIdx.x >> 6, lane = threadIdx.x & 63;
  const int row0 = lb * 16 + wave * 4;
  float esum = 0.f;
#pragma unroll
  for (int k = 0; k < 4; ++k) {
    int row = row0 + k;
    const float* wr = w + (size_t)row * h;
    float acc = 0.f;
    if (h == 512) {
      const float4* wr4 = (const float4*)wr; const float4* sh4 = (const float4*)sh;
#pragma unroll
      for (int j = 0; j < 2; ++j) {
        float4 a = wr4[lane + j * 64]; float4 c = sh4[lane + j * 64];
        acc += a.x * c.x + a.y * c.y + a.z * c.z + a.w * c.w;
      }
    } else if (h == 256) {
      float4 a = ((const float4*)wr)[lane]; float4 c = ((const float4*)sh)[lane];
      acc = a.x * c.x + a.y * c.y + a.z * c.z + a.w * c.w;
    } else if (h == 128) {
      float2 a = ((const float2*)wr)[lane]; float2 c = ((const float2*)sh)[lane];
      acc = a.x * c.x + a.y * c.y;
    } else {
      acc = wr[lane] * sh[lane];
    }
    acc = wave_sum(acc);
    if (lane == 0) { ws[coff + row] = acc; esum += expf(acc); }
  }
  __shared__ float wred[4];
  if (lane == 0) wred[wave] = esum;
  __syncthreads();
  if (threadIdx.x == 0) ws[poff + lb] = wred[0] + wred[1] + wred[2] + wred[3];
}

// Kernel 3: reduce partial exp-sums -> log-sum-exps, gather targets, mean.
__global__ __launch_bounds__(256) void finalize_kernel(
    const int* __restrict__ targets, const float* __restrict__ ws,
    float* __restrict__ out) {
  __shared__ float red[256];
  float lse[5];
  const int offs[5] = {OFF_PH, OFF_P0, OFF_P1, OFF_P2, OFF_P3};
  const int lens[5] = {626, 625, 1250, 2500, 1250};
  for (int s = 0; s < 5; ++s) {
    float v = 0.f;
    for (int i = threadIdx.x; i < lens[s]; i += 256) v += ws[offs[s] + i];
    red[threadIdx.x] = v; __syncthreads();
    for (int st = 128; st; st >>= 1) {
      if (threadIdx.x < st) red[threadIdx.x] += red[threadIdx.x + st];
      __syncthreads();
    }
    lse[s] = logf(red[0]);
    __syncthreads();
  }
  // head logprob of each cluster gate (rows 10000..10003)
  const float clh0 = ws[10000] - lse[0];
  const float clh1 = ws[10001] - lse[0];
  const float clh2 = ws[10002] - lse[0];
  const float clh3 = ws[10003] - lse[0];
  float s = 0.f;
  for (int i = threadIdx.x; i < 4096; i += 256) {
    int t = targets[i]; float lp;
    if (t < 10000)      lp = ws[OFF_HEAD + t] - lse[0];
    else if (t < 20000) lp = ws[OFF_C0 + t - 10000] - lse[1] + clh0;
    else if (t < 40000) lp = ws[OFF_C1 + t - 20000] - lse[2] + clh1;
    else if (t < 80000) lp = ws[OFF_C2 + t - 40000] - lse[3] + clh2;
    else                lp = ws[OFF_C3 + t - 80000] - lse[4] + clh3;
    s += lp;
  }
  red[threadIdx.x] = s; __syncthreads();
  for (int st = 128; st; st >>= 1) {
    if (threadIdx.x < st) red[threadIdx.x] += red[threadIdx.x + st];
    __syncthreads();
  }
  if (threadIdx.x == 0) out[0] = -red[0] / 4096.f;
}

extern "C" void kernel_launch(void* const* d_in, const int* in_sizes, int n_in,
                              void* d_out, int out_size, void* d_ws, size_t ws_size,
                              hipStream_t stream) {
  const float* feat    = (const float*)d_in[0];
  const int*   targets = (const int*)d_in[1];
  const float* head_w  = (const float*)d_in[2];
  const float* t0p = (const float*)d_in[3];
  const float* t0w = (const float*)d_in[4];
  const float* t1p = (const float*)d_in[5];
  const float* t1w = (const float*)d_in[6];
  const float* t2p = (const float*)d_in[7];
  const float* t2w = (const float*)d_in[8];
  const float* t3p = (const float*)d_in[9];
  const float* t3w = (const float*)d_in[10];
  float* ws  = (float*)d_ws;
  float* out = (float*)d_out;

  head_proj_kernel<<<686, 256, 0, stream>>>(feat, head_w, t0p, t1p, t2p, t3p, ws);
  tail_kernel<<<5625, 256, 0, stream>>>(t0w, t1w, t2w, t3w, ws);
  finalize_kernel<<<1, 256, 0, stream>>>(targets, ws, out);
}